// Round 2
// baseline (852.782 us; speedup 1.0000x reference)
//
#include <hip/hip_runtime.h>
#include <stdint.h>

#define Bn 32
#define Nn 1723
#define Cn 512
#define Hn 256
#define NP 1728   // padded N for support^T rows
#define MT 27     // ceil(1723/64)
#define KS 54     // ceil(1728/32)

typedef __bf16 bf16x8 __attribute__((ext_vector_type(8)));
typedef float f32x4 __attribute__((ext_vector_type(4)));
typedef unsigned short u16;

__device__ __forceinline__ u16 f2b(float f){
  union{float f; uint32_t i;} c; c.f=f; uint32_t u=c.i;
  u += 0x7fffu + ((u>>16)&1u);
  return (u16)(u>>16);
}
__device__ __forceinline__ bf16x8 ld8(const u16* p){
  union{ uint4 u; bf16x8 b; } c;
  c.u = *reinterpret_cast<const uint4*>(p);
  return c.b;
}
__device__ __forceinline__ f32x4 mfma16(bf16x8 a, bf16x8 b, f32x4 c){
  return __builtin_amdgcn_mfma_f32_16x16x32_bf16(a,b,c,0,0,0);
}

// ---------------- kernel 0: f32 weights -> bf16 (and transpose conv_W) ----------------
__global__ __launch_bounds__(256) void k_prep(
    const float* __restrict__ W1, const float* __restrict__ Wc, const float* __restrict__ W2,
    u16* __restrict__ W1b, u16* __restrict__ WcTb, u16* __restrict__ W2b)
{
  const int i = blockIdx.x*256 + threadIdx.x;   // grid 512*256 = 131072
  W1b[i] = f2b(W1[i]);
  W2b[i] = f2b(W2[i]);
  if (i < 65536){
    const int n = i & 255, k = i >> 8;          // read coalesced over n? (k*256+n with i fast in n)
    WcTb[n*256 + k] = f2b(Wc[k*256 + n]);
  }
}

// ---------------- stage A: x -> support^T ----------------
// grid (27, 32), block 256. Wave w owns A-rows 16w..16w+15 of the 64-row tile.
__global__ __launch_bounds__(256) void k_stageA(
    const float* __restrict__ x, const float* __restrict__ prw, const float* __restrict__ prb,
    const u16* __restrict__ W1, const float* __restrict__ b1,
    const float* __restrict__ n1w, const float* __restrict__ n1b,
    const u16* __restrict__ WcT, u16* __restrict__ supT)
{
  __shared__ u16 t1[64*512];   // 64 KB, XOR-swizzled rows
  __shared__ u16 t2[64*256];   // 32 KB
  const int b = blockIdx.y;
  const int m0 = blockIdx.x*64;
  const int tid = threadIdx.x;
  const int w = tid>>6, l = tid&63, lr = l&15, lh = l>>4;

  // ---- phase 1: LN(x)+relu -> t1 (bf16) ----
  float pw[8], pb[8];
  #pragma unroll
  for (int j=0;j<8;++j){ pw[j]=prw[l*8+j]; pb[j]=prb[l*8+j]; }
  for (int rr=0; rr<16; ++rr){
    const int rloc = w*16+rr;
    int rg = m0 + rloc; rg = rg < Nn ? rg : Nn-1;   // clamp phantom rows (finite, masked later)
    const float* src = x + ((size_t)b*Nn + rg)*Cn + l*8;
    float4 c0 = *reinterpret_cast<const float4*>(src);
    float4 c1 = *reinterpret_cast<const float4*>(src+4);
    float v[8] = {c0.x,c0.y,c0.z,c0.w,c1.x,c1.y,c1.z,c1.w};
    float s=0.f, q=0.f;
    #pragma unroll
    for (int j=0;j<8;++j){ s+=v[j]; q+=v[j]*v[j]; }
    #pragma unroll
    for (int m=1;m<64;m<<=1){ s += __shfl_xor(s,m); q += __shfl_xor(q,m); }
    const float mean = s*(1.f/Cn);
    const float rstd = rsqrtf(fmaxf(q*(1.f/Cn) - mean*mean, 0.f) + 1e-12f);
    union{uint4 u; u16 s[8];} ov;
    #pragma unroll
    for (int j=0;j<8;++j){
      float t = (v[j]-mean)*rstd*pw[j] + pb[j];
      ov.s[j] = f2b(fmaxf(t,0.f));
    }
    const int idx = (rloc*512 + l*8) ^ ((rloc&7)<<3);
    *reinterpret_cast<uint4*>(&t1[idx]) = ov.u;
  }
  __syncthreads();

  // ---- phase 2: GEMM1  y1[64x256] = t1 @ W1^T  (K=512) ----
  f32x4 acc[16];
  #pragma unroll
  for (int i=0;i<16;++i) acc[i] = f32x4{0.f,0.f,0.f,0.f};
  const int arow = w*16 + lr;
  const int aswz = (arow&7)<<3;
  for (int kk=0; kk<16; ++kk){
    bf16x8 a = ld8(&t1[(arow*512 + kk*32 + lh*8) ^ aswz]);
    #pragma unroll
    for (int nt=0; nt<16; ++nt){
      bf16x8 bb = ld8(W1 + (size_t)(nt*16+lr)*Cn + kk*32 + lh*8);
      acc[nt] = mfma16(a, bb, acc[nt]);
    }
  }

  // ---- phase 3: +b1, LN(256), relu -> t2 ----
  float sum[4]={0,0,0,0}, sq[4]={0,0,0,0};
  #pragma unroll
  for (int nt=0; nt<16; ++nt){
    const float bias = b1[nt*16+lr];
    #pragma unroll
    for (int r=0;r<4;++r){
      float vv = acc[nt][r] + bias;
      acc[nt][r] = vv; sum[r]+=vv; sq[r]+=vv*vv;
    }
  }
  #pragma unroll
  for (int m=1;m<16;m<<=1){
    #pragma unroll
    for (int r=0;r<4;++r){ sum[r]+=__shfl_xor(sum[r],m); sq[r]+=__shfl_xor(sq[r],m); }
  }
  float mean[4], rstd[4];
  #pragma unroll
  for (int r=0;r<4;++r){
    mean[r] = sum[r]*(1.f/Hn);
    rstd[r] = rsqrtf(fmaxf(sq[r]*(1.f/Hn) - mean[r]*mean[r], 0.f) + 1e-12f);
  }
  #pragma unroll
  for (int nt=0; nt<16; ++nt){
    const int col = nt*16+lr;
    const float nw = n1w[col], nb = n1b[col];
    #pragma unroll
    for (int r=0;r<4;++r){
      const int row = w*16 + lh*4 + r;
      float t = (acc[nt][r]-mean[r])*rstd[r]*nw + nb;
      t2[(row*256 + col) ^ ((row&7)<<3)] = f2b(fmaxf(t,0.f));
    }
  }
  __syncthreads();

  // ---- phase 4: GEMM2  support[64x256] = t2 @ conv_W  (K=256, B from WcT) ----
  f32x4 acc2[16];
  #pragma unroll
  for (int i=0;i<16;++i) acc2[i] = f32x4{0.f,0.f,0.f,0.f};
  for (int kk=0; kk<8; ++kk){
    bf16x8 a = ld8(&t2[(arow*256 + kk*32 + lh*8) ^ aswz]);
    #pragma unroll
    for (int nt=0; nt<16; ++nt){
      bf16x8 bb = ld8(WcT + (size_t)(nt*16+lr)*Hn + kk*32 + lh*8);
      acc2[nt] = mfma16(a, bb, acc2[nt]);
    }
  }

  // ---- phase 5: write support^T [B][H][NP] (bf16) ----
  #pragma unroll
  for (int nt=0; nt<16; ++nt){
    const int h = nt*16+lr;
    const size_t base = ((size_t)b*Hn + h)*NP + m0 + w*16 + lh*4;
    ushort4 o;
    o.x = f2b(acc2[nt][0]); o.y = f2b(acc2[nt][1]);
    o.z = f2b(acc2[nt][2]); o.w = f2b(acc2[nt][3]);
    *reinterpret_cast<ushort4*>(supT + base) = o;
  }
}

// ---------------- stage B: adj @ support -> +cb -> LN -> relu -> @lin2 -> +x ----------------
// grid (27, 32), block 256. Wave w: GEMM1 cols 64w..64w+63, GEMM2 cols 128w..128w+127.
__global__ __launch_bounds__(256) void k_stageB(
    const float* __restrict__ adj, const u16* __restrict__ supT,
    const float* __restrict__ cb, const float* __restrict__ n2w, const float* __restrict__ n2b,
    const u16* __restrict__ W2, const float* __restrict__ bl2,
    const float* __restrict__ x, float* __restrict__ out)
{
  __shared__ u16 atile[2][64*64];   // adj tile as bf16: [row][k0..31] stride 64, swizzled
  __shared__ u16 t3[64*256];        // 32 KB
  __shared__ float ps[4][64], pq[4][64];
  const int b = blockIdx.y, m0 = blockIdx.x*64;
  const int tid = threadIdx.x, w = tid>>6, l = tid&63, lr = l&15, lh = l>>4;
  const int kc = tid&31, r0 = tid>>5;

  auto stage = [&](int buf, int s){
    const int kg = s*32 + kc;
    const bool kok = kg < Nn;
    #pragma unroll
    for (int p=0;p<8;++p){
      const int row = r0 + p*8;
      int rg = m0 + row; rg = rg < Nn ? rg : Nn-1;
      float v = kok ? adj[((size_t)b*Nn + rg)*Nn + kg] : 0.f;
      atile[buf][(row*64 + kc) ^ ((row&7)<<3)] = f2b(v);
    }
  };

  // ---- GEMM1: O1[64x256] = adj_tile @ support  (K=1728, double-buffered adj) ----
  f32x4 acc1[4][4];
  #pragma unroll
  for (int i=0;i<4;++i)
    #pragma unroll
    for (int j=0;j<4;++j) acc1[i][j] = f32x4{0.f,0.f,0.f,0.f};

  stage(0,0);
  __syncthreads();
  for (int s=0; s<KS; ++s){
    const int cur = s&1;
    if (s+1 < KS) stage(cur^1, s+1);
    bf16x8 bb[4];
    #pragma unroll
    for (int nt=0;nt<4;++nt)
      bb[nt] = ld8(supT + ((size_t)b*Hn + w*64 + nt*16 + lr)*NP + s*32 + lh*8);
    #pragma unroll
    for (int mt=0;mt<4;++mt){
      const int row = mt*16+lr;
      bf16x8 a = ld8(&atile[cur][(row*64 + lh*8) ^ ((row&7)<<3)]);
      #pragma unroll
      for (int nt=0;nt<4;++nt) acc1[mt][nt] = mfma16(a, bb[nt], acc1[mt][nt]);
    }
    __syncthreads();
  }

  // ---- +conv_b, LN(256) across waves, relu -> t3 ----
  float sum[4][4], sq[4][4];
  #pragma unroll
  for (int mt=0;mt<4;++mt)
    #pragma unroll
    for (int r=0;r<4;++r){ sum[mt][r]=0.f; sq[mt][r]=0.f; }
  float biasv[4];
  #pragma unroll
  for (int nt=0;nt<4;++nt) biasv[nt] = cb[w*64+nt*16+lr];
  #pragma unroll
  for (int mt=0;mt<4;++mt)
    #pragma unroll
    for (int nt=0;nt<4;++nt)
      #pragma unroll
      for (int r=0;r<4;++r){
        float vv = acc1[mt][nt][r] + biasv[nt];
        acc1[mt][nt][r] = vv; sum[mt][r]+=vv; sq[mt][r]+=vv*vv;
      }
  #pragma unroll
  for (int m=1;m<16;m<<=1){
    #pragma unroll
    for (int mt=0;mt<4;++mt)
      #pragma unroll
      for (int r=0;r<4;++r){ sum[mt][r]+=__shfl_xor(sum[mt][r],m); sq[mt][r]+=__shfl_xor(sq[mt][r],m); }
  }
  if (lr==0){
    #pragma unroll
    for (int mt=0;mt<4;++mt)
      #pragma unroll
      for (int r=0;r<4;++r){
        const int row = mt*16+lh*4+r;
        ps[w][row]=sum[mt][r]; pq[w][row]=sq[mt][r];
      }
  }
  __syncthreads();
  float meanv[4][4], rstdv[4][4];
  #pragma unroll
  for (int mt=0;mt<4;++mt)
    #pragma unroll
    for (int r=0;r<4;++r){
      const int row = mt*16+lh*4+r;
      const float S = ps[0][row]+ps[1][row]+ps[2][row]+ps[3][row];
      const float Q = pq[0][row]+pq[1][row]+pq[2][row]+pq[3][row];
      const float mu = S*(1.f/Hn);
      meanv[mt][r] = mu;
      rstdv[mt][r] = rsqrtf(fmaxf(Q*(1.f/Hn)-mu*mu, 0.f) + 1e-12f);
    }
  #pragma unroll
  for (int nt=0;nt<4;++nt){
    const int col = w*64+nt*16+lr;
    const float nw = n2w[col], nb = n2b[col];
    #pragma unroll
    for (int mt=0;mt<4;++mt)
      #pragma unroll
      for (int r=0;r<4;++r){
        const int row = mt*16+lh*4+r;
        float t = (acc1[mt][nt][r]-meanv[mt][r])*rstdv[mt][r]*nw + nb;
        t3[(row*256+col) ^ ((row&7)<<3)] = f2b(fmaxf(t,0.f));
      }
  }
  __syncthreads();

  // ---- GEMM2: y[64x512] = t3 @ lin2_W^T  (K=256) ----
  f32x4 acc2[4][8];
  #pragma unroll
  for (int i=0;i<4;++i)
    #pragma unroll
    for (int j=0;j<8;++j) acc2[i][j] = f32x4{0.f,0.f,0.f,0.f};
  for (int kk=0;kk<8;++kk){
    bf16x8 a[4];
    #pragma unroll
    for (int mt=0;mt<4;++mt){
      const int row = mt*16+lr;
      a[mt] = ld8(&t3[(row*256 + kk*32 + lh*8) ^ ((row&7)<<3)]);
    }
    #pragma unroll
    for (int nt=0;nt<8;++nt){
      bf16x8 bb = ld8(W2 + (size_t)(w*128+nt*16+lr)*Hn + kk*32 + lh*8);
      #pragma unroll
      for (int mt=0;mt<4;++mt) acc2[mt][nt] = mfma16(a[mt], bb, acc2[mt][nt]);
    }
  }

  // ---- epilogue: +lin2_b + x residual -> out (f32) ----
  #pragma unroll
  for (int nt=0;nt<8;++nt){
    const int col = w*128 + nt*16 + lr;
    const float bias = bl2[col];
    #pragma unroll
    for (int mt=0;mt<4;++mt){
      #pragma unroll
      for (int r=0;r<4;++r){
        const int mg = m0 + mt*16 + lh*4 + r;
        if (mg < Nn){
          const size_t off = ((size_t)b*Nn + mg)*Cn + col;
          out[off] = acc2[mt][nt][r] + bias + x[off];
        }
      }
    }
  }
}

extern "C" void kernel_launch(void* const* d_in, const int* in_sizes, int n_in,
                              void* d_out, int out_size, void* d_ws, size_t ws_size,
                              hipStream_t stream){
  const float* x    = (const float*)d_in[0];
  const float* adj  = (const float*)d_in[1];
  const float* prw  = (const float*)d_in[2];
  const float* prb  = (const float*)d_in[3];
  const float* W1   = (const float*)d_in[4];
  const float* b1   = (const float*)d_in[5];
  const float* n1w  = (const float*)d_in[6];
  const float* n1b  = (const float*)d_in[7];
  const float* Wc   = (const float*)d_in[8];
  const float* cbv  = (const float*)d_in[9];
  const float* n2w  = (const float*)d_in[10];
  const float* n2b  = (const float*)d_in[11];
  const float* W2   = (const float*)d_in[12];
  const float* bl2  = (const float*)d_in[13];

  u16* ws    = (u16*)d_ws;
  u16* W1b   = ws;                          // 131072 u16
  u16* WcTb  = ws + 131072;                 // 65536
  u16* W2b   = ws + 131072 + 65536;         // 131072
  u16* supT  = ws + 131072 + 65536 + 131072; // 32*256*1728 u16 (~27 MB)

  k_prep<<<dim3(512), dim3(256), 0, stream>>>(W1, Wc, W2, W1b, WcTb, W2b);
  k_stageA<<<dim3(MT,Bn), dim3(256), 0, stream>>>(x, prw, prb, W1b, b1, n1w, n1b, WcTb, supT);
  k_stageB<<<dim3(MT,Bn), dim3(256), 0, stream>>>(adj, supT, cbv, n2w, n2b, W2b, bl2, x, (float*)d_out);
}

// Round 3
// 504.996 us; speedup vs baseline: 1.6887x; 1.6887x over previous
//
#include <hip/hip_runtime.h>
#include <stdint.h>

#define Bn 32
#define Nn 1723
#define Cn 512
#define Hn 256
#define NP 1728   // padded N for support^T cols
#define MTA 54    // ceil(1723/32) stage-A tiles
#define MTB 27    // ceil(1723/64) stage-B tiles
#define KS2 27    // 1728/64 K-steps in stage B

typedef __bf16 bf16x8 __attribute__((ext_vector_type(8)));
typedef float f32x4 __attribute__((ext_vector_type(4)));
typedef unsigned short u16;

__device__ __forceinline__ u16 f2b(float f){
  union{float f; uint32_t i;} c; c.f=f; uint32_t u=c.i;
  u += 0x7fffu + ((u>>16)&1u);
  return (u16)(u>>16);
}
__device__ __forceinline__ bf16x8 ld8(const u16* p){
  union{ uint4 u; bf16x8 b; } c;
  c.u = *reinterpret_cast<const uint4*>(p);
  return c.b;
}
__device__ __forceinline__ f32x4 mfma16(bf16x8 a, bf16x8 b, f32x4 c){
  return __builtin_amdgcn_mfma_f32_16x16x32_bf16(a,b,c,0,0,0);
}

// ---------------- kernel 0: f32 weights -> bf16 (and transpose conv_W) ----------------
__global__ __launch_bounds__(256) void k_prep(
    const float* __restrict__ W1, const float* __restrict__ Wc, const float* __restrict__ W2,
    u16* __restrict__ W1b, u16* __restrict__ WcTb, u16* __restrict__ W2b)
{
  const int i = blockIdx.x*256 + threadIdx.x;   // grid 512*256 = 131072
  W1b[i] = f2b(W1[i]);
  W2b[i] = f2b(W2[i]);
  if (i < 65536){
    const int n = i & 255, k = i >> 8;
    WcTb[n*256 + k] = f2b(Wc[k*256 + n]);
  }
}

// ---------------- stage A: x -> support^T ----------------
// grid (54, 32), block 256 = 4 waves as 2x2 (wm, wn). 32-row tile -> 48.5 KB LDS, 3 blocks/CU.
__global__ __launch_bounds__(256) void k_stageA(
    const float* __restrict__ x, const float* __restrict__ prw, const float* __restrict__ prb,
    const u16* __restrict__ W1, const float* __restrict__ b1,
    const float* __restrict__ n1w, const float* __restrict__ n1b,
    const u16* __restrict__ WcT, u16* __restrict__ supT)
{
  __shared__ u16 t1[32*512];   // 32 KB, XOR-swizzled rows
  __shared__ u16 t2[32*256];   // 16 KB
  __shared__ float ps[2][32], pq[2][32];
  const int b = blockIdx.y;
  const int m0 = blockIdx.x*32;
  const int tid = threadIdx.x;
  const int w = tid>>6, l = tid&63, lr = l&15, lh = l>>4;
  const int wm = w>>1, wn = w&1;

  // ---- phase 1: LN(x)+relu -> t1 (bf16), 8 rows per wave ----
  float pw[8], pb[8];
  #pragma unroll
  for (int j=0;j<8;++j){ pw[j]=prw[l*8+j]; pb[j]=prb[l*8+j]; }
  #pragma unroll
  for (int rr=0; rr<8; ++rr){
    const int rloc = w*8+rr;
    int rg = m0 + rloc; rg = rg < Nn ? rg : Nn-1;   // clamp phantom rows (finite, masked later)
    const float* src = x + ((size_t)b*Nn + rg)*Cn + l*8;
    float4 c0 = *reinterpret_cast<const float4*>(src);
    float4 c1 = *reinterpret_cast<const float4*>(src+4);
    float v[8] = {c0.x,c0.y,c0.z,c0.w,c1.x,c1.y,c1.z,c1.w};
    float s=0.f, q=0.f;
    #pragma unroll
    for (int j=0;j<8;++j){ s+=v[j]; q+=v[j]*v[j]; }
    #pragma unroll
    for (int m=1;m<64;m<<=1){ s += __shfl_xor(s,m); q += __shfl_xor(q,m); }
    const float mean = s*(1.f/Cn);
    const float rstd = rsqrtf(fmaxf(q*(1.f/Cn) - mean*mean, 0.f) + 1e-12f);
    union{uint4 u; u16 s[8];} ov;
    #pragma unroll
    for (int j=0;j<8;++j){
      float t = (v[j]-mean)*rstd*pw[j] + pb[j];
      ov.s[j] = f2b(fmaxf(t,0.f));
    }
    const int idx = (rloc*512 + l*8) ^ ((rloc&7)<<3);
    *reinterpret_cast<uint4*>(&t1[idx]) = ov.u;
  }
  __syncthreads();

  // ---- phase 2: GEMM1  y1[32x256] = t1 @ W1^T  (K=512); wave: rows wm*16, cols wn*128 ----
  f32x4 acc[8];
  #pragma unroll
  for (int i=0;i<8;++i) acc[i] = f32x4{0.f,0.f,0.f,0.f};
  const int arow = wm*16 + lr;
  const int aswz = (arow&7)<<3;
  for (int kk=0; kk<16; ++kk){
    bf16x8 a = ld8(&t1[(arow*512 + kk*32 + lh*8) ^ aswz]);
    #pragma unroll
    for (int nt=0; nt<8; ++nt){
      bf16x8 bb = ld8(W1 + (size_t)(wn*128+nt*16+lr)*Cn + kk*32 + lh*8);
      acc[nt] = mfma16(a, bb, acc[nt]);
    }
  }

  // ---- phase 3: +b1, LN(256) across wn pairs, relu -> t2 ----
  float sum[4]={0,0,0,0}, sq[4]={0,0,0,0};
  #pragma unroll
  for (int nt=0; nt<8; ++nt){
    const float bias = b1[wn*128+nt*16+lr];
    #pragma unroll
    for (int r=0;r<4;++r){
      float vv = acc[nt][r] + bias;
      acc[nt][r] = vv; sum[r]+=vv; sq[r]+=vv*vv;
    }
  }
  #pragma unroll
  for (int m=1;m<16;m<<=1){
    #pragma unroll
    for (int r=0;r<4;++r){ sum[r]+=__shfl_xor(sum[r],m); sq[r]+=__shfl_xor(sq[r],m); }
  }
  if (lr==0){
    #pragma unroll
    for (int r=0;r<4;++r){
      const int row = wm*16 + lh*4 + r;
      ps[wn][row]=sum[r]; pq[wn][row]=sq[r];
    }
  }
  __syncthreads();
  float mean[4], rstd[4];
  #pragma unroll
  for (int r=0;r<4;++r){
    const int row = wm*16 + lh*4 + r;
    const float S = ps[0][row]+ps[1][row];
    const float Q = pq[0][row]+pq[1][row];
    const float mu = S*(1.f/Hn);
    mean[r] = mu;
    rstd[r] = rsqrtf(fmaxf(Q*(1.f/Hn) - mu*mu, 0.f) + 1e-12f);
  }
  #pragma unroll
  for (int nt=0; nt<8; ++nt){
    const int col = wn*128+nt*16+lr;
    const float nw = n1w[col], nb = n1b[col];
    #pragma unroll
    for (int r=0;r<4;++r){
      const int row = wm*16 + lh*4 + r;
      float t = (acc[nt][r]-mean[r])*rstd[r]*nw + nb;
      t2[(row*256 + col) ^ ((row&7)<<3)] = f2b(fmaxf(t,0.f));
    }
  }
  __syncthreads();

  // ---- phase 4: GEMM2  support[32x256] = t2 @ conv_W  (K=256, B from WcT) ----
  f32x4 acc2[8];
  #pragma unroll
  for (int i=0;i<8;++i) acc2[i] = f32x4{0.f,0.f,0.f,0.f};
  for (int kk=0; kk<8; ++kk){
    bf16x8 a = ld8(&t2[(arow*256 + kk*32 + lh*8) ^ aswz]);
    #pragma unroll
    for (int nt=0; nt<8; ++nt){
      bf16x8 bb = ld8(WcT + (size_t)(wn*128+nt*16+lr)*Hn + kk*32 + lh*8);
      acc2[nt] = mfma16(a, bb, acc2[nt]);
    }
  }

  // ---- phase 5: write support^T [B][H][NP] (bf16) ----
  #pragma unroll
  for (int nt=0; nt<8; ++nt){
    const int h = wn*128+nt*16+lr;
    const size_t base = ((size_t)b*Hn + h)*NP + m0 + wm*16 + lh*4;
    ushort4 o;
    o.x = f2b(acc2[nt][0]); o.y = f2b(acc2[nt][1]);
    o.z = f2b(acc2[nt][2]); o.w = f2b(acc2[nt][3]);
    *reinterpret_cast<ushort4*>(supT + base) = o;
  }
}

// ---------------- stage B: adj @ support -> +cb -> LN -> relu -> @lin2 -> +x ----------------
// grid 864 (1-D, XCD-bijective: 4 consecutive b per XCD for supT L2 residency), block 256.
// K-step 64, reg-staged adj prefetch (2-phase pipeline), GEMM2 in two 64-col halves.
__global__ __launch_bounds__(256) void k_stageB(
    const float* __restrict__ adj, const u16* __restrict__ supT,
    const float* __restrict__ cb, const float* __restrict__ n2w, const float* __restrict__ n2b,
    const u16* __restrict__ W2, const float* __restrict__ bl2,
    const float* __restrict__ x, float* __restrict__ out)
{
  __shared__ u16 atile[2][64*64];   // adj tile bf16, swizzled; 16 KB
  __shared__ u16 t3[64*256];        // 32 KB
  __shared__ float ps[4][64], pq[4][64];
  const int bid = blockIdx.x;
  const int xcd = bid & 7, idx = bid >> 3;
  const int b = xcd*4 + (idx & 3);          // 4 consecutive b per XCD
  const int m0 = (idx >> 2) * 64;
  const int tid = threadIdx.x, w = tid>>6, l = tid&63, lr = l&15, lh = l>>4;
  const int sc = tid & 63;                  // staging col within K-step
  const int sr0 = tid >> 6;                 // staging row base

  const float* adjb = adj + (size_t)b*Nn*Nn;

  float pf[16];
  auto issue = [&](int s){
    const int kg = s*64 + sc;
    const bool kok = kg < Nn;
    #pragma unroll
    for (int i=0;i<16;++i){
      int rg = m0 + sr0 + 4*i; rg = rg < Nn ? rg : Nn-1;
      pf[i] = kok ? adjb[(size_t)rg*Nn + kg] : 0.f;
    }
  };
  auto commit = [&](int buf){
    #pragma unroll
    for (int i=0;i<16;++i){
      const int row = sr0 + 4*i;
      atile[buf][(row*64 + sc) ^ ((row&7)<<3)] = f2b(pf[i]);
    }
  };

  // ---- GEMM1: O1[64x256] = adj_tile @ support  (K=1728) ----
  f32x4 acc1[4][4];
  #pragma unroll
  for (int i=0;i<4;++i)
    #pragma unroll
    for (int j=0;j<4;++j) acc1[i][j] = f32x4{0.f,0.f,0.f,0.f};

  issue(0);
  commit(0);
  __syncthreads();
  for (int s=0; s<KS2; ++s){
    const int cur = s&1;
    if (s+1 < KS2) issue(s+1);              // VMEM issue early; consumed after MFMA
    bf16x8 bb[8];
    #pragma unroll
    for (int kk=0;kk<2;++kk)
      #pragma unroll
      for (int nt=0;nt<4;++nt)
        bb[kk*4+nt] = ld8(supT + ((size_t)b*Hn + w*64 + nt*16 + lr)*NP + s*64 + kk*32 + lh*8);
    #pragma unroll
    for (int kk=0;kk<2;++kk)
      #pragma unroll
      for (int mt=0;mt<4;++mt){
        const int row = mt*16+lr;
        bf16x8 a = ld8(&atile[cur][(row*64 + kk*32 + lh*8) ^ ((row&7)<<3)]);
        #pragma unroll
        for (int nt=0;nt<4;++nt) acc1[mt][nt] = mfma16(a, bb[kk*4+nt], acc1[mt][nt]);
      }
    if (s+1 < KS2) commit(cur^1);
    __syncthreads();
  }

  // ---- +conv_b, LN(256) across waves, relu -> t3 ----
  float sum[4][4], sq[4][4];
  #pragma unroll
  for (int mt=0;mt<4;++mt)
    #pragma unroll
    for (int r=0;r<4;++r){ sum[mt][r]=0.f; sq[mt][r]=0.f; }
  float biasv[4];
  #pragma unroll
  for (int nt=0;nt<4;++nt) biasv[nt] = cb[w*64+nt*16+lr];
  #pragma unroll
  for (int mt=0;mt<4;++mt)
    #pragma unroll
    for (int nt=0;nt<4;++nt)
      #pragma unroll
      for (int r=0;r<4;++r){
        float vv = acc1[mt][nt][r] + biasv[nt];
        acc1[mt][nt][r] = vv; sum[mt][r]+=vv; sq[mt][r]+=vv*vv;
      }
  #pragma unroll
  for (int m=1;m<16;m<<=1){
    #pragma unroll
    for (int mt=0;mt<4;++mt)
      #pragma unroll
      for (int r=0;r<4;++r){ sum[mt][r]+=__shfl_xor(sum[mt][r],m); sq[mt][r]+=__shfl_xor(sq[mt][r],m); }
  }
  if (lr==0){
    #pragma unroll
    for (int mt=0;mt<4;++mt)
      #pragma unroll
      for (int r=0;r<4;++r){
        const int row = mt*16+lh*4+r;
        ps[w][row]=sum[mt][r]; pq[w][row]=sq[mt][r];
      }
  }
  __syncthreads();
  float meanv[4][4], rstdv[4][4];
  #pragma unroll
  for (int mt=0;mt<4;++mt)
    #pragma unroll
    for (int r=0;r<4;++r){
      const int row = mt*16+lh*4+r;
      const float S = ps[0][row]+ps[1][row]+ps[2][row]+ps[3][row];
      const float Q = pq[0][row]+pq[1][row]+pq[2][row]+pq[3][row];
      const float mu = S*(1.f/Hn);
      meanv[mt][r] = mu;
      rstdv[mt][r] = rsqrtf(fmaxf(Q*(1.f/Hn)-mu*mu, 0.f) + 1e-12f);
    }
  #pragma unroll
  for (int nt=0;nt<4;++nt){
    const int col = w*64+nt*16+lr;
    const float nw = n2w[col], nb = n2b[col];
    #pragma unroll
    for (int mt=0;mt<4;++mt)
      #pragma unroll
      for (int r=0;r<4;++r){
        const int row = mt*16+lh*4+r;
        float t = (acc1[mt][nt][r]-meanv[mt][r])*rstdv[mt][r]*nw + nb;
        t3[(row*256+col) ^ ((row&7)<<3)] = f2b(fmaxf(t,0.f));
      }
  }
  __syncthreads();

  // ---- GEMM2 (two 64-col halves to cap VGPRs): y[64x512] = t3 @ lin2_W^T (K=256) ----
  #pragma unroll
  for (int h=0; h<2; ++h){
    f32x4 acc2[4][4];
    #pragma unroll
    for (int i=0;i<4;++i)
      #pragma unroll
      for (int j=0;j<4;++j) acc2[i][j] = f32x4{0.f,0.f,0.f,0.f};
    for (int kk=0;kk<8;++kk){
      bf16x8 a[4];
      #pragma unroll
      for (int mt=0;mt<4;++mt){
        const int row = mt*16+lr;
        a[mt] = ld8(&t3[(row*256 + kk*32 + lh*8) ^ ((row&7)<<3)]);
      }
      #pragma unroll
      for (int nt=0;nt<4;++nt){
        bf16x8 bb = ld8(W2 + (size_t)(w*128 + h*64 + nt*16+lr)*Hn + kk*32 + lh*8);
        #pragma unroll
        for (int mt=0;mt<4;++mt) acc2[mt][nt] = mfma16(a[mt], bb, acc2[mt][nt]);
      }
    }
    // ---- epilogue: +lin2_b + x residual -> out (f32) ----
    #pragma unroll
    for (int nt=0;nt<4;++nt){
      const int col = w*128 + h*64 + nt*16 + lr;
      const float bias = bl2[col];
      #pragma unroll
      for (int mt=0;mt<4;++mt){
        #pragma unroll
        for (int r=0;r<4;++r){
          const int mg = m0 + mt*16 + lh*4 + r;
          if (mg < Nn){
            const size_t off = ((size_t)b*Nn + mg)*Cn + col;
            out[off] = acc2[mt][nt][r] + bias + x[off];
          }
        }
      }
    }
  }
}

extern "C" void kernel_launch(void* const* d_in, const int* in_sizes, int n_in,
                              void* d_out, int out_size, void* d_ws, size_t ws_size,
                              hipStream_t stream){
  const float* x    = (const float*)d_in[0];
  const float* adj  = (const float*)d_in[1];
  const float* prw  = (const float*)d_in[2];
  const float* prb  = (const float*)d_in[3];
  const float* W1   = (const float*)d_in[4];
  const float* b1   = (const float*)d_in[5];
  const float* n1w  = (const float*)d_in[6];
  const float* n1b  = (const float*)d_in[7];
  const float* Wc   = (const float*)d_in[8];
  const float* cbv  = (const float*)d_in[9];
  const float* n2w  = (const float*)d_in[10];
  const float* n2b  = (const float*)d_in[11];
  const float* W2   = (const float*)d_in[12];
  const float* bl2  = (const float*)d_in[13];

  u16* ws    = (u16*)d_ws;
  u16* W1b   = ws;                           // 131072 u16
  u16* WcTb  = ws + 131072;                  // 65536
  u16* W2b   = ws + 131072 + 65536;          // 131072
  u16* supT  = ws + 131072 + 65536 + 131072; // 32*256*1728 u16 (~27 MB)

  k_prep<<<dim3(512), dim3(256), 0, stream>>>(W1, Wc, W2, W1b, WcTb, W2b);
  k_stageA<<<dim3(MTA,Bn), dim3(256), 0, stream>>>(x, prw, prb, W1b, b1, n1w, n1b, WcTb, supT);
  k_stageB<<<dim3(MTB*Bn), dim3(256), 0, stream>>>(adj, supT, cbv, n2w, n2b, W2b, bl2, x, (float*)d_out);
}